// Round 16
// baseline (208.717 us; speedup 1.0000x reference)
//
#include <hip/hip_runtime.h>
#include <stdint.h>

// ClusterHead: P = softmax_k( x . c_k - 0.5*||c_k||^2 )   (||x||^2 cancels)
// R16: persistent 2-tile blocks (grid 256 = 1/CU) + vmcnt-free barriers.
// All barriers = s_waitcnt lgkmcnt(0) ; s_barrier  (LDS-only ordering) --
// __syncthreads' implicit vmcnt(0) was serializing the 131MB NT-store drain
// against the next phase. Now tile 0's stores drain under tile 1's
// stage+K-loop; only the final half-drain is exposed.
// K-loop = R15: 16 waves (4/SIMD, <=128 regs), depth-3 half-slice B ring,
// 5-bit XOR swizzle (0 bank conflicts), barrier-free, single-term fp16
// (absmax 0.0078), 32x32x16 f16 MFMA, NT x-loads / out-stores.
// B-pack: 32 images of 32KB, image j (T=j>>1, ks=j&1): [cb(32)]
// [(c32*2+kh)*8] halfwords -> byte offset j*32768.

namespace {
constexpr int N_ROWS  = 32768;
constexpr int K_CL    = 1024;
constexpr int D_DIM   = 512;
constexpr int BM      = 64;
constexpr int THREADS = 1024;
constexpr int WAVES   = 16;
constexpr int NBLOCKS = 256;
constexpr int TILES_PER_BLOCK = 2;
}

typedef _Float16 f16_t;
typedef _Float16 f16x8 __attribute__((ext_vector_type(8)));
typedef _Float16 f16x4 __attribute__((ext_vector_type(4)));
typedef float    f32x16 __attribute__((ext_vector_type(16)));
typedef float    f32x4v __attribute__((ext_vector_type(4)));

// LDS-only fence: per-wave lgkm drain THEN barrier => all waves' LDS writes
// visible after it, while global (NT store / prefetch) traffic keeps flying.
#define LFENCE                                                                 \
  asm volatile("s_waitcnt lgkmcnt(0)" ::: "memory");                           \
  __builtin_amdgcn_s_barrier();                                                \
  __builtin_amdgcn_sched_barrier(0);

// ---- prep: fp16 B-pack + bias = -0.5*||c||^2 (fp32 exact) ----
__global__ __launch_bounds__(64) void prep_kernel(const float* __restrict__ centers,
                                                  f16_t* __restrict__ bpack,
                                                  float* __restrict__ bias) {
  const int col = blockIdx.x, lane = threadIdx.x;
  const int t  = lane >> 2;          // k-slice (d>>5)
  const int ks = (lane >> 1) & 1;    // 16-k group
  const int kh = lane & 1;           // 8-k half
  const float* src = centers + (size_t)col * D_DIM + lane * 8;
  f16x8 hi;
  float ssq = 0.f;
  #pragma unroll
  for (int i = 0; i < 8; ++i) {
    float v = src[i];
    ssq += v * v;
    hi[i] = (f16_t)v;
  }
  const int cb = col >> 5, c32 = col & 31;
  *(f16x8*)(bpack + (size_t)(t * 2 + ks) * 16384 + cb * 512 + (c32 * 2 + kh) * 8) = hi;
  for (int o = 32; o; o >>= 1) ssq += __shfl_down(ssq, o, 64);
  if (lane == 0) bias[col] = -0.5f * ssq;
}

// ---- main fused kernel: persistent, 2 tiles of 64 rows x 1024 cols ----
__global__ __launch_bounds__(THREADS, 4) void cluster_kernel(
    const float* __restrict__ x, const f16_t* __restrict__ bpack,
    const float* __restrict__ bias, float* __restrict__ out) {
  __shared__ __align__(16) char Ax[65536];   // 64KB swizzled A panel
  __shared__ float red[WAVES * BM];          // 4KB
  __shared__ float fin[BM];

  const int tid  = threadIdx.x;
  const int w    = tid >> 6;       // wave 0..15 -> cols [w*64, +64)
  const int lane = tid & 63;
  const int l31  = lane & 31;
  const int h    = lane >> 5;

  // per-lane byte base into an image: wave's cb-pair at w*2048
  const char* bbase = (const char*)bpack + w * 2048 + (l31 * 2 + h) * 16;
  const char* abase = Ax + l31 * 1024;
  const int swz = l31 << 4;        // 5-bit row XOR (bits 4-8)

  float bcol[2];
  #pragma unroll
  for (int cc = 0; cc < 2; ++cc)
    bcol[cc] = bias[w * 64 + cc * 32 + l31];

  f16x8 hb[3][2];
#define LOADHB(J)                                                              \
  {                                                                            \
    const char* p_ = bbase + (size_t)(J) * 32768;                              \
    hb[(J) % 3][0] = *(const f16x8*)(p_);                                      \
    hb[(J) % 3][1] = *(const f16x8*)(p_ + 1024);                               \
  }

  #pragma unroll 1
  for (int rt = 0; rt < TILES_PER_BLOCK; ++rt) {
    const int brow = (blockIdx.x + rt * NBLOCKS) * BM;

    // first B half-slices in flight during staging
    LOADHB(0)
    LOADHB(1)

    // ---- stage A panel -> LDS fp16 (coalesced NT reads, swz5 writes) ----
    {
      const float* xsrc = x + (size_t)brow * D_DIM;
      #pragma unroll
      for (int it = 0; it < 8; ++it) {
        const int idx = it * 1024 + tid;       // float4 index (64*128 total)
        const int r = idx >> 7, f = idx & 127;
        f32x4v v = __builtin_nontemporal_load(
            (const f32x4v*)(xsrc + (size_t)r * D_DIM + f * 4));
        f16x4 h4;
        h4[0] = (f16_t)v[0]; h4[1] = (f16_t)v[1];
        h4[2] = (f16_t)v[2]; h4[3] = (f16_t)v[3];
        *(f16x4*)(Ax + r * 1024 + ((f * 8) ^ ((r & 31) << 4))) = h4;
      }
    }
    LFENCE   // LDS writes visible; tile t-1's stores keep draining

    f32x16 acc[2][2];
    #pragma unroll
    for (int rb = 0; rb < 2; ++rb)
      #pragma unroll
      for (int cc = 0; cc < 2; ++cc)
        #pragma unroll
        for (int e = 0; e < 16; ++e) acc[rb][cc][e] = 0.f;

    // ---- K loop: 32 half-slices, depth-3 rolling B ring, barrier-free ----
    #pragma unroll
    for (int j = 0; j < 32; ++j) {
      if (j + 2 < 32) { LOADHB(j + 2) }
      const int o = (((j >> 1) * 64 + (j & 1) * 32 + h * 16)) ^ swz;
      const f16x8 a0 = *(const f16x8*)(abase + o);
      const f16x8 a1 = *(const f16x8*)(abase + 32768 + o);
      acc[0][0] = __builtin_amdgcn_mfma_f32_32x32x16_f16(a0, hb[j % 3][0], acc[0][0], 0, 0, 0);
      acc[0][1] = __builtin_amdgcn_mfma_f32_32x32x16_f16(a0, hb[j % 3][1], acc[0][1], 0, 0, 0);
      acc[1][0] = __builtin_amdgcn_mfma_f32_32x32x16_f16(a1, hb[j % 3][0], acc[1][0], 0, 0, 0);
      acc[1][1] = __builtin_amdgcn_mfma_f32_32x32x16_f16(a1, hb[j % 3][1], acc[1][1], 0, 0, 0);
    }

    // ---- epilogue: fused softmax over 1024 columns ----
    // col(cc) = w*64 + cc*32 + l31 ; row(rb,reg) = rb*32+(reg&3)+8*(reg>>2)+4*h
    #pragma unroll
    for (int rb = 0; rb < 2; ++rb)
      #pragma unroll
      for (int reg = 0; reg < 16; ++reg) {
        float v0 = acc[rb][0][reg] + bcol[0];
        float v1 = acc[rb][1][reg] + bcol[1];
        acc[rb][0][reg] = v0;
        acc[rb][1][reg] = v1;
        float m = fmaxf(v0, v1);
        m = fmaxf(m, __shfl_xor(m, 1, 64));
        m = fmaxf(m, __shfl_xor(m, 2, 64));
        m = fmaxf(m, __shfl_xor(m, 4, 64));
        m = fmaxf(m, __shfl_xor(m, 8, 64));
        m = fmaxf(m, __shfl_xor(m, 16, 64));
        if (l31 == 0)
          red[w * BM + rb * 32 + (reg & 3) + 8 * (reg >> 2) + 4 * h] = m;
      }
    LFENCE
    if (tid < BM) {
      float m = red[tid];
      #pragma unroll
      for (int ww = 1; ww < WAVES; ++ww) m = fmaxf(m, red[ww * BM + tid]);
      fin[tid] = m;
    }
    LFENCE   // fin visible; red reads done

    #pragma unroll
    for (int rb = 0; rb < 2; ++rb)
      #pragma unroll
      for (int reg = 0; reg < 16; ++reg) {
        const float m = fin[rb * 32 + (reg & 3) + 8 * (reg >> 2) + 4 * h];
        float e0 = __expf(acc[rb][0][reg] - m);
        float e1 = __expf(acc[rb][1][reg] - m);
        acc[rb][0][reg] = e0;
        acc[rb][1][reg] = e1;
        float s = e0 + e1;
        s += __shfl_xor(s, 1, 64);
        s += __shfl_xor(s, 2, 64);
        s += __shfl_xor(s, 4, 64);
        s += __shfl_xor(s, 8, 64);
        s += __shfl_xor(s, 16, 64);
        if (l31 == 1)    // distinct lane; same row coverage
          red[w * BM + rb * 32 + (reg & 3) + 8 * (reg >> 2) + 4 * h] = s;
      }
    LFENCE
    if (tid < BM) {
      float s = 0.f;
      #pragma unroll
      for (int ww = 0; ww < WAVES; ++ww) s += red[ww * BM + tid];
      fin[tid] = 1.0f / s;
    }
    LFENCE

    // NT stores: issued, never waited on inside the kernel
    #pragma unroll
    for (int rb = 0; rb < 2; ++rb)
      #pragma unroll
      for (int reg = 0; reg < 16; ++reg) {
        const int row = rb * 32 + (reg & 3) + 8 * (reg >> 2) + 4 * h;
        const float rs = fin[row];
        #pragma unroll
        for (int cc = 0; cc < 2; ++cc)
          __builtin_nontemporal_store(acc[rb][cc][reg] * rs,
              &out[(size_t)(brow + row) * K_CL + w * 64 + cc * 32 + l31]);
      }
    // next tile's stage overwrites Ax only after its LFENCE (all waves here)
  }
}

extern "C" void kernel_launch(void* const* d_in, const int* in_sizes, int n_in,
                              void* d_out, int out_size, void* d_ws, size_t ws_size,
                              hipStream_t stream) {
  const float* x       = (const float*)d_in[0];   // [32768, 512] fp32
  const float* centers = (const float*)d_in[1];   // [1024, 512] fp32
  float* out = (float*)d_out;                     // [32768, 1024] fp32

  f16_t* bpack = (f16_t*)d_ws;                                   // 32*32KB = 1MB
  float* bias  = (float*)((char*)d_ws + (size_t)32 * 32768);     // 4KB

  prep_kernel<<<K_CL, 64, 0, stream>>>(centers, bpack, bias);
  cluster_kernel<<<NBLOCKS, THREADS, 0, stream>>>(x, bpack, bias, out);
}

// Round 17
// 93.928 us; speedup vs baseline: 2.2221x; 2.2221x over previous
//
#include <hip/hip_runtime.h>
#include <stdint.h>

// ClusterHead: P = softmax_k( x . c_k - 0.5*||c_k||^2 )   (||x||^2 cancels)
// R17 = R11 (best, 89us) with ONE change: output stores are REGULAR
// (L2/L3-cached) instead of nontemporal. Theory: NT stores bypass L2+L3 and
// force a synchronous ~131MB HBM drain inside the dispatch (pure-write
// ceiling << 6.3TB/s copy figure); regular stores land in L2 and the 256MB
// L3 absorbs the drain lazily/overlapped. x loads KEEP nontemporal (protects
// L2-resident B-pack -- the validated half of R8's gain).
// Structure: single-term fp16 GEMM (absmax 0.0078), 32x32x16 f16 MFMA,
// whole 64x512 A-panel staged once to LDS (XOR swizzle), barrier-free
// K-loop, B global->VGPR full-slice reg double-buffer.
// B-pack: 32 sub-images of 32KB; s = 2t + jh; within: [ks(2)][cb(16)]
// [(c32*2+kh)*8] halfwords. A LDS: row-major [64][512] f16, byte offset
// row*1024 + (k*2 ^ ((row&7)<<4)).

namespace {
constexpr int N_ROWS  = 32768;
constexpr int K_CL    = 1024;
constexpr int D_DIM   = 512;
constexpr int BM      = 64;
constexpr int THREADS = 512;
constexpr int WAVES   = 8;
constexpr int NSLICE  = 16;     // k-slices of 32
}

typedef _Float16 f16_t;
typedef _Float16 f16x8 __attribute__((ext_vector_type(8)));
typedef _Float16 f16x4 __attribute__((ext_vector_type(4)));
typedef float    f32x16 __attribute__((ext_vector_type(16)));
typedef float    f32x4v __attribute__((ext_vector_type(4)));

// ---- prep: fp16 B-pack + bias = -0.5*||c||^2 (fp32 exact) ----
__global__ __launch_bounds__(64) void prep_kernel(const float* __restrict__ centers,
                                                  f16_t* __restrict__ bpack,
                                                  float* __restrict__ bias) {
  const int col = blockIdx.x, lane = threadIdx.x;
  const int t  = lane >> 2;          // k-slice of this lane's 8 d's
  const int ks = (lane >> 1) & 1;    // 16-k group
  const int kh = lane & 1;           // 8-k half
  const float* src = centers + (size_t)col * D_DIM + lane * 8;
  f16x8 hi;
  float ssq = 0.f;
  #pragma unroll
  for (int i = 0; i < 8; ++i) {
    float v = src[i];
    ssq += v * v;
    hi[i] = (f16_t)v;
  }
  const int jh = col >> 9, cb = (col & 511) >> 5, c32 = col & 31;
  const size_t off = ((size_t)ks * 16 + cb) * 512 + (c32 * 2 + kh) * 8;  // halfwords
  *(f16x8*)(bpack + (size_t)(2 * t + jh) * 16384 + off) = hi;
  for (int o = 32; o; o >>= 1) ssq += __shfl_down(ssq, o, 64);
  if (lane == 0) bias[col] = -0.5f * ssq;
}

// ---- main fused kernel: 64 rows x 1024 cols per block ----
__global__ __launch_bounds__(THREADS, 2) void cluster_kernel(
    const float* __restrict__ x, const f16_t* __restrict__ bpack,
    const float* __restrict__ bias, float* __restrict__ out) {
  __shared__ __align__(16) char Ax[64 * 1024];   // 64KB swizzled A panel
  __shared__ float red[WAVES * BM];              // 2KB
  __shared__ float fin[BM];

  const int tid  = threadIdx.x;
  const int wid  = tid >> 6;
  const int lane = tid & 63;
  const int l31  = lane & 31;
  const int h    = lane >> 5;
  const int brow = blockIdx.x * BM;

  // per-lane byte base into a B sub-image (wave's 2 cb-blocks at wid*2048)
  const char* bbase = (const char*)bpack + wid * 2048 + (l31 * 2 + h) * 16;

#define LOADB8(S, DST)                                                         \
  {                                                                            \
    const char* p_ = bbase + (size_t)((S) & 31) * 32768;                       \
    (DST)[0] = *(const f16x8*)(p_);            /* jh0 ks0 cb-even */           \
    (DST)[1] = *(const f16x8*)(p_ + 1024);     /* jh0 ks0 cb-odd  */           \
    (DST)[2] = *(const f16x8*)(p_ + 16384);    /* jh0 ks1 cb-even */           \
    (DST)[3] = *(const f16x8*)(p_ + 17408);    /* jh0 ks1 cb-odd  */           \
    (DST)[4] = *(const f16x8*)(p_ + 32768);    /* jh1 ks0 cb-even */           \
    (DST)[5] = *(const f16x8*)(p_ + 33792);    /* jh1 ks0 cb-odd  */           \
    (DST)[6] = *(const f16x8*)(p_ + 49152);    /* jh1 ks1 cb-even */           \
    (DST)[7] = *(const f16x8*)(p_ + 50176);    /* jh1 ks1 cb-odd  */           \
  }
#define COMPUTE16(B)                                                           \
  {                                                                            \
    _Pragma("unroll")                                                          \
    for (int j2_ = 0; j2_ < 2; ++j2_)                                          \
      _Pragma("unroll")                                                        \
      for (int ks_ = 0; ks_ < 2; ++ks_)                                        \
        _Pragma("unroll")                                                      \
        for (int c2_ = 0; c2_ < 2; ++c2_)                                      \
          _Pragma("unroll")                                                    \
          for (int rb_ = 0; rb_ < 2; ++rb_)                                    \
            acc[rb_][j2_ * 2 + c2_] = __builtin_amdgcn_mfma_f32_32x32x16_f16(  \
                a[rb_][ks_], (B)[j2_ * 4 + ks_ * 2 + c2_],                     \
                acc[rb_][j2_ * 2 + c2_], 0, 0, 0);                             \
  }

  f16x8 bA[8], bB[8];

  // issue first slice's B loads before staging (covers L2 latency)
  LOADB8(0, bA)

  // ---- stage x panel -> LDS fp16 (coalesced NT reads, swizzled writes) ----
  {
    const float* xsrc = x + (size_t)brow * D_DIM;
    #pragma unroll
    for (int it = 0; it < 16; ++it) {
      const int idx = it * 512 + tid;            // float4 index
      const int r = idx >> 7, f = idx & 127;
      f32x4v v = __builtin_nontemporal_load(
          (const f32x4v*)(xsrc + (size_t)r * D_DIM + f * 4));
      f16x4 h4;
      h4[0] = (f16_t)v[0]; h4[1] = (f16_t)v[1];
      h4[2] = (f16_t)v[2]; h4[3] = (f16_t)v[3];
      *(f16x4*)(Ax + r * 1024 + ((f * 8) ^ ((r & 7) << 4))) = h4;
    }
  }
  __syncthreads();   // the ONLY pre-epilogue barrier

  f32x16 acc[2][4];
  #pragma unroll
  for (int rb = 0; rb < 2; ++rb)
    #pragma unroll
    for (int cc = 0; cc < 4; ++cc)
      #pragma unroll
      for (int e = 0; e < 16; ++e) acc[rb][cc][e] = 0.f;

  const char* abase0 = Ax + l31 * 1024;          // rb=0 rows; rb=1 at +32KB
  const int swz = (l31 & 7) << 4;
  const int h16 = h * 16;
  f16x8 a[2][2];

  // ---- main loop: 16 slices, barrier-free ----
  #pragma unroll
  for (int tt = 0; tt < 8; ++tt) {
    {  // slice T = 2*tt : compute bA, prefetch bB
      const int T = 2 * tt;
      LOADB8(2 * (T + 1), bB)
      const int o0 = (T * 64 + h16) ^ swz;
      const int o1 = o0 ^ 32;
      a[0][0] = *(const f16x8*)(abase0 + o0);
      a[0][1] = *(const f16x8*)(abase0 + o1);
      a[1][0] = *(const f16x8*)(abase0 + 32768 + o0);
      a[1][1] = *(const f16x8*)(abase0 + 32768 + o1);
      COMPUTE16(bA)
    }
    {  // slice T = 2*tt+1 : compute bB, prefetch bA
      const int T = 2 * tt + 1;
      if (T < 15) LOADB8(2 * (T + 1), bA)
      const int o0 = (T * 64 + h16) ^ swz;
      const int o1 = o0 ^ 32;
      a[0][0] = *(const f16x8*)(abase0 + o0);
      a[0][1] = *(const f16x8*)(abase0 + o1);
      a[1][0] = *(const f16x8*)(abase0 + 32768 + o0);
      a[1][1] = *(const f16x8*)(abase0 + 32768 + o1);
      COMPUTE16(bB)
    }
  }

  // ---- epilogue: fused softmax over 1024 columns ----
  // col(cc) = (cc>>1)*512 + wid*64 + (cc&1)*32 + l31
  // row(rb,reg) = rb*32 + (reg&3) + 8*(reg>>2) + 4*h
  float bcol[4];
  #pragma unroll
  for (int cc = 0; cc < 4; ++cc)
    bcol[cc] = bias[(cc >> 1) * 512 + wid * 64 + (cc & 1) * 32 + l31];

  float rr[2][16];
  #pragma unroll
  for (int rb = 0; rb < 2; ++rb)
    #pragma unroll
    for (int reg = 0; reg < 16; ++reg) {
      float m = -3.0e38f;
      #pragma unroll
      for (int cc = 0; cc < 4; ++cc) {
        float v = acc[rb][cc][reg] + bcol[cc];
        acc[rb][cc][reg] = v;
        m = fmaxf(m, v);
      }
      m = fmaxf(m, __shfl_xor(m, 1, 64));
      m = fmaxf(m, __shfl_xor(m, 2, 64));
      m = fmaxf(m, __shfl_xor(m, 4, 64));
      m = fmaxf(m, __shfl_xor(m, 8, 64));
      m = fmaxf(m, __shfl_xor(m, 16, 64));
      rr[rb][reg] = m;
    }
  __syncthreads();   // all waves past the K-loop before red reuse
  if (l31 == 0) {    // lanes 0 and 32 (h=0,1) cover distinct rows
    #pragma unroll
    for (int rb = 0; rb < 2; ++rb)
      #pragma unroll
      for (int reg = 0; reg < 16; ++reg)
        red[wid * BM + rb * 32 + (reg & 3) + 8 * (reg >> 2) + 4 * h] = rr[rb][reg];
  }
  __syncthreads();
  if (tid < BM) {
    float m = red[tid];
    #pragma unroll
    for (int w = 1; w < WAVES; ++w) m = fmaxf(m, red[w * BM + tid]);
    fin[tid] = m;
  }
  __syncthreads();

  #pragma unroll
  for (int rb = 0; rb < 2; ++rb)
    #pragma unroll
    for (int reg = 0; reg < 16; ++reg) {
      const float m = fin[rb * 32 + (reg & 3) + 8 * (reg >> 2) + 4 * h];
      float s = 0.f;
      #pragma unroll
      for (int cc = 0; cc < 4; ++cc) {
        float e = __expf(acc[rb][cc][reg] - m);
        acc[rb][cc][reg] = e;
        s += e;
      }
      s += __shfl_xor(s, 1, 64);
      s += __shfl_xor(s, 2, 64);
      s += __shfl_xor(s, 4, 64);
      s += __shfl_xor(s, 8, 64);
      s += __shfl_xor(s, 16, 64);
      rr[rb][reg] = s;
    }
  __syncthreads();   // fin(max) reads done before red overwrite
  if (l31 == 0) {
    #pragma unroll
    for (int rb = 0; rb < 2; ++rb)
      #pragma unroll
      for (int reg = 0; reg < 16; ++reg)
        red[wid * BM + rb * 32 + (reg & 3) + 8 * (reg >> 2) + 4 * h] = rr[rb][reg];
  }
  __syncthreads();
  if (tid < BM) {
    float s = 0.f;
    #pragma unroll
    for (int w = 0; w < WAVES; ++w) s += red[w * BM + tid];
    fin[tid] = 1.0f / s;
  }
  __syncthreads();

  // ---- stores: REGULAR (L2/L3-cached), not nontemporal ----
  #pragma unroll
  for (int rb = 0; rb < 2; ++rb)
    #pragma unroll
    for (int reg = 0; reg < 16; ++reg) {
      const int row = rb * 32 + (reg & 3) + 8 * (reg >> 2) + 4 * h;
      const float rs = fin[row];
      #pragma unroll
      for (int cc = 0; cc < 4; ++cc) {
        const int col = (cc >> 1) * 512 + wid * 64 + (cc & 1) * 32 + l31;
        out[(size_t)(brow + row) * K_CL + col] = acc[rb][cc][reg] * rs;
      }
    }
}

extern "C" void kernel_launch(void* const* d_in, const int* in_sizes, int n_in,
                              void* d_out, int out_size, void* d_ws, size_t ws_size,
                              hipStream_t stream) {
  const float* x       = (const float*)d_in[0];   // [32768, 512] fp32
  const float* centers = (const float*)d_in[1];   // [1024, 512] fp32
  float* out = (float*)d_out;                     // [32768, 1024] fp32

  f16_t* bpack = (f16_t*)d_ws;                                   // 32*32KB = 1MB
  float* bias  = (float*)((char*)d_ws + (size_t)32 * 32768);     // 4KB

  prep_kernel<<<K_CL, 64, 0, stream>>>(centers, bpack, bias);
  cluster_kernel<<<N_ROWS / BM, THREADS, 0, stream>>>(x, bpack, bias, out);
}